// Round 2
// baseline (389.781 us; speedup 1.0000x reference)
//
#include <hip/hip_runtime.h>

#define LTC_B 512
#define LTC_H 512
#define LTC_I 256

static constexpr float kL2E = 1.4426950408889634f;  // log2(e)

// Pre-transformed weight cell: t = a*v + c (log2 domain), sig = 1/(1+2^t),
// n += wz*sig, d += wd*sig.
struct alignas(8) H4 { _Float16 a, c, wz, wd; };

typedef unsigned int u32;
#define AS_G __attribute__((address_space(1)))
#define AS_L __attribute__((address_space(3)))

__device__ __forceinline__ void ldg_lds16(const void* g, void* l) {
    // async global->LDS DMA, 16B per lane; LDS dest = uniform base + lane*16
    __builtin_amdgcn_global_load_lds((const AS_G u32*)g, (AS_L u32*)l, 16, 0, 0);
}

// Transform (mu, sigma, W, erev) -> H4 slab in h-tile-major layout:
// slab[ht][j][hh] with ht = h>>6, hh = h&63. Each (ht, 64-j chunk) is a
// contiguous 32KB block -> perfect for global_load_lds staging.
__global__ void ltc_prep(const float* __restrict__ mu, const float* __restrict__ sigma,
                         const float* __restrict__ W, const float* __restrict__ erev,
                         H4* __restrict__ slab, int K) {
    int idx = blockIdx.x * 256 + threadIdx.x;
    if (idx >= K * LTC_H) return;
    int j = idx >> 9, h = idx & 511;
    float sg = sigma[idx], m = mu[idx], w = W[idx], ev = erev[idx];
    H4 o;
    o.a  = (_Float16)(-sg * kL2E);
    o.c  = (_Float16)(m * sg * kL2E);
    o.wz = (_Float16)(w * ev);
    o.wd = (_Float16)(w);
    slab[((h >> 6) * K + j) * 64 + (h & 63)] = o;
}

// One pass over the reduction dim K. Block = 128 threads (2 waves), each wave
// owns 2 batch rows x 64 h. Grid = (8 h-tiles, B/4 b-tiles) = 1024 blocks
// -> 4 blocks/CU, barrier stalls of one block overlap compute of the others.
template<int K, bool RECUR>
__global__ __launch_bounds__(128, 2)
void ltc_pass(const float* __restrict__ vsrc,    // B x K
              const H4* __restrict__ slab,       // [8][K][64]
              const float* __restrict__ snum, const float* __restrict__ sden,
              const float* __restrict__ vleak, const float* __restrict__ gleak,
              const float* __restrict__ cm,
              float* __restrict__ onum, float* __restrict__ oden,
              float* __restrict__ vout)
{
    __shared__ H4 wbuf[64 * 64];                 // one 64-j chunk, 32KB
    const int tid  = threadIdx.x;
    const int lane = tid & 63;
    const int wave = tid >> 6;                   // 0..1
    const int ht   = blockIdx.x;                 // 0..7
    const int b0   = blockIdx.y * 4 + wave * 2;
    const int b1   = b0 + 1;

    // v rows resident in VGPRs: lane holds v[b][g*64+lane]
    constexpr int NG = K / 64;
    float v0r[NG], v1r[NG];
    #pragma unroll
    for (int g = 0; g < NG; ++g) {
        v0r[g] = vsrc[b0 * K + g * 64 + lane];
        v1r[g] = vsrc[b1 * K + g * 64 + lane];
    }

    const char* slabt = (const char*)(slab + ht * (K * 64));
    float n0 = 0.f, d0 = 0.f, n1 = 0.f, d1 = 0.f;

    for (int g = 0; g < NG; ++g) {
        __syncthreads();                         // wbuf readers from prev chunk done
        const char* src = slabt + g * 32768;
        char* dst = (char*)wbuf;
        for (int r = wave; r < 32; r += 2)       // 32 rows x 1KB, split by wave
            ldg_lds16(src + r * 1024 + lane * 16, dst + r * 1024);
        __syncthreads();                         // drains the DMA (vmcnt) + joins

        #pragma unroll
        for (int jj = 0; jj < 64; ++jj) {
            H4 wv = wbuf[jj * 64 + lane];        // ds_read_b64, 2-way alias = free
            float a  = (float)wv.a,  c  = (float)wv.c;
            float wz = (float)wv.wz, wd = (float)wv.wd;
            // wave-uniform v via readlane (constant index under full unroll)
            float vj0 = __int_as_float(__builtin_amdgcn_readlane(__float_as_int(v0r[g]), jj));
            float vj1 = __int_as_float(__builtin_amdgcn_readlane(__float_as_int(v1r[g]), jj));
            float t0 = fmaf(a, vj0, c);
            float t1 = fmaf(a, vj1, c);
            float e0 = __builtin_amdgcn_exp2f(t0);
            float e1 = __builtin_amdgcn_exp2f(t1);
            float s0 = __builtin_amdgcn_rcpf(1.0f + e0);
            float s1 = __builtin_amdgcn_rcpf(1.0f + e1);
            n0 = fmaf(wz, s0, n0);  d0 = fmaf(wd, s0, d0);
            n1 = fmaf(wz, s1, n1);  d1 = fmaf(wd, s1, d1);
        }
    }

    const int h = ht * 64 + lane;
    if constexpr (RECUR) {
        const float gl = gleak[h], vl = vleak[h], c = cm[h];
        const float glvl = gl * vl;
        const float vp0 = v0r[ht];               // K==512: v[b][h], h = ht*64+lane
        const float vp1 = v1r[ht];
        float num0 = fmaf(c, vp0, glvl) + n0 + snum[b0 * LTC_H + h];
        float den0 = c + gl + d0 + sden[b0 * LTC_H + h];
        vout[b0 * LTC_H + h] = num0 * __builtin_amdgcn_rcpf(den0 + 1e-8f);
        float num1 = fmaf(c, vp1, glvl) + n1 + snum[b1 * LTC_H + h];
        float den1 = c + gl + d1 + sden[b1 * LTC_H + h];
        vout[b1 * LTC_H + h] = num1 * __builtin_amdgcn_rcpf(den1 + 1e-8f);
    } else {
        onum[b0 * LTC_H + h] = n0;  oden[b0 * LTC_H + h] = d0;
        onum[b1 * LTC_H + h] = n1;  oden[b1 * LTC_H + h] = d1;
    }
}

extern "C" void kernel_launch(void* const* d_in, const int* in_sizes, int n_in,
                              void* d_out, int out_size, void* d_ws, size_t ws_size,
                              hipStream_t stream) {
    const float* inputs = (const float*)d_in[0];   // B x I
    const float* state  = (const float*)d_in[1];   // B x H
    const float* smu    = (const float*)d_in[2];   // I x H
    const float* ssig   = (const float*)d_in[3];
    const float* sW     = (const float*)d_in[4];
    const float* serev  = (const float*)d_in[5];
    const float* mu     = (const float*)d_in[6];   // H x H
    const float* sig    = (const float*)d_in[7];
    const float* W      = (const float*)d_in[8];
    const float* erev   = (const float*)d_in[9];
    const float* vleak  = (const float*)d_in[10];  // H
    const float* gleak  = (const float*)d_in[11];
    const float* cm     = (const float*)d_in[12];

    float* out  = (float*)d_out;                   // B x H
    char*  ws   = (char*)d_ws;
    float* snum = (float*)(ws);                              // 1MB
    float* sden = (float*)(ws + 1 * 1048576);                // 1MB
    float* vA   = (float*)(ws + 2 * 1048576);                // 1MB ping buffer
    H4*    rslab = (H4*)(ws + 3 * 1048576);                  // 2MB (H x H)
    H4*    sslab = (H4*)(ws + 5 * 1048576);                  // 1MB (I x H)

    // Prep: transform weights once per launch.
    ltc_prep<<<(LTC_H * LTC_H + 255) / 256, 256, 0, stream>>>(mu, sig, W, erev, rslab, LTC_H);
    ltc_prep<<<(LTC_I * LTC_H + 255) / 256, 256, 0, stream>>>(smu, ssig, sW, serev, sslab, LTC_I);

    dim3 grid(LTC_H / 64, LTC_B / 4);              // (8, 128) = 1024 blocks
    dim3 blk(128);

    // Sensory pass: raw sums into ws.
    ltc_pass<LTC_I, false><<<grid, blk, 0, stream>>>(
        inputs, sslab, nullptr, nullptr, nullptr, nullptr, nullptr,
        snum, sden, nullptr);

    // 6 unfolds, ping-ponging so the last lands in d_out.
    const float* vin = state;
    float* targets[6] = {vA, out, vA, out, vA, out};
    for (int s = 0; s < 6; ++s) {
        ltc_pass<LTC_H, true><<<grid, blk, 0, stream>>>(
            vin, rslab, snum, sden, vleak, gleak, cm,
            nullptr, nullptr, targets[s]);
        vin = targets[s];
    }
}

// Round 3
// 336.120 us; speedup vs baseline: 1.1596x; 1.1596x over previous
//
#include <hip/hip_runtime.h>

#define LTC_B 512
#define LTC_H 512
#define LTC_I 256

static constexpr float kL2E = 1.4426950408889634f;  // log2(e)

// Pre-transformed weight cell: t = a*v + c (log2 domain), sig = 1/(1+2^t),
// n += wz*sig, d += wd*sig.
struct alignas(8)  H4   { _Float16 a, c, wz, wd; };
struct alignas(16) H4x2 { H4 e[2]; };                // j-pair for one h

typedef unsigned int u32;
#define AS_G __attribute__((address_space(1)))
#define AS_L __attribute__((address_space(3)))

__device__ __forceinline__ void ldg_lds16(const void* g, void* l) {
    // async global->LDS DMA, 16B per lane; LDS dest = uniform base + lane*16
    __builtin_amdgcn_global_load_lds((const AS_G u32*)g, (AS_L u32*)l, 16, 0, 0);
}

// slab layout: 16B unit ((ht*(K/2) + jp)*64 + hh) holds j=2jp (e[0]) and
// j=2jp+1 (e[1]) for h = ht*64+hh. Each 32-j chunk of one h-tile is a
// contiguous 16KB block -> global_load_lds staging with zero address VALU.
__global__ void ltc_prep(const float* __restrict__ mu, const float* __restrict__ sigma,
                         const float* __restrict__ W, const float* __restrict__ erev,
                         H4x2* __restrict__ slab, int K) {
    int idx = blockIdx.x * 256 + threadIdx.x;
    if (idx >= K * LTC_H) return;
    int j = idx >> 9, h = idx & 511;
    float sg = sigma[idx], m = mu[idx], w = W[idx], ev = erev[idx];
    H4 o;
    o.a  = (_Float16)(-sg * kL2E);
    o.c  = (_Float16)(m * sg * kL2E);
    o.wz = (_Float16)(w * ev);
    o.wd = (_Float16)(w);
    slab[((h >> 6) * (K >> 1) + (j >> 1)) * 64 + (h & 63)].e[j & 1] = o;
}

// One pass over reduction dim K. Block = 256 threads (4 waves), each wave owns
// ONE batch row x 64 h. Grid (8 h-tiles, B/4) = 1024 blocks -> 4 blocks/CU,
// 16 waves/CU (4/SIMD). Double-buffered 16KB chunks: barrier drains chunk c's
// DMA, chunk c+1's DMA is issued before computing chunk c.
template<int K, bool RECUR>
__global__ __launch_bounds__(256, 4)
void ltc_pass(const float* __restrict__ vsrc,    // B x K
              const H4x2* __restrict__ slab,     // [8][K/2][64]
              const float* __restrict__ snum, const float* __restrict__ sden,
              const float* __restrict__ vleak, const float* __restrict__ gleak,
              const float* __restrict__ cm,
              float* __restrict__ onum, float* __restrict__ oden,
              float* __restrict__ vout)
{
    __shared__ H4x2 wbuf[2][16 * 64];            // 2 x 16KB
    const int tid  = threadIdx.x;
    const int lane = tid & 63;
    const int wave = tid >> 6;                   // 0..3
    const int ht   = blockIdx.x;                 // 0..7
    const int b    = blockIdx.y * 4 + wave;

    // v row resident in VGPRs: vr[g] = v[b][g*64+lane]
    constexpr int NG = K / 64;
    float vr[NG];
    #pragma unroll
    for (int g = 0; g < NG; ++g) vr[g] = vsrc[b * K + g * 64 + lane];

    const char* slabt = (const char*)slab + (size_t)ht * (K * 512);  // K*64*8 B
    constexpr int NC = K / 32;
    float n = 0.f, d = 0.f;

    // prefetch chunk 0
    {
        char* dst = (char*)&wbuf[0][0];
        #pragma unroll
        for (int r = 0; r < 4; ++r) {
            const int row = wave * 4 + r;        // 16 rows x 1KB, 4 waves
            ldg_lds16(slabt + row * 1024 + lane * 16, dst + row * 1024);
        }
    }

    #pragma unroll
    for (int c = 0; c < NC; ++c) {
        __syncthreads();                         // drains chunk c's DMA + joins
        if (c + 1 < NC) {                        // DMA c+1 flies during compute c
            const char* src = slabt + (c + 1) * 16384;
            char* dst = (char*)&wbuf[(c + 1) & 1][0];
            #pragma unroll
            for (int r = 0; r < 4; ++r) {
                const int row = wave * 4 + r;
                ldg_lds16(src + row * 1024 + lane * 16, dst + row * 1024);
            }
        }
        const H4x2* wb = &wbuf[c & 1][0];
        constexpr int dummy = 0; (void)dummy;
        const int g = c >> 1;                    // constant: c-loop fully unrolled
        const int joff = (c & 1) * 32;
        #pragma unroll
        for (int jj = 0; jj < 16; ++jj) {
            H4x2 pr = wb[jj * 64 + lane];        // ds_read_b128
            float vj0 = __int_as_float(__builtin_amdgcn_readlane(__float_as_int(vr[g]), joff + jj * 2));
            float vj1 = __int_as_float(__builtin_amdgcn_readlane(__float_as_int(vr[g]), joff + jj * 2 + 1));
            float t0 = fmaf((float)pr.e[0].a, vj0, (float)pr.e[0].c);   // v_fma_mix
            float t1 = fmaf((float)pr.e[1].a, vj1, (float)pr.e[1].c);
            float e0 = __builtin_amdgcn_exp2f(t0);
            float e1 = __builtin_amdgcn_exp2f(t1);
            float s0 = __builtin_amdgcn_rcpf(1.0f + e0);
            float s1 = __builtin_amdgcn_rcpf(1.0f + e1);
            n = fmaf((float)pr.e[0].wz, s0, n);
            d = fmaf((float)pr.e[0].wd, s0, d);
            n = fmaf((float)pr.e[1].wz, s1, n);
            d = fmaf((float)pr.e[1].wd, s1, d);
        }
    }

    const int h  = ht * 64 + lane;
    const int bh = b * LTC_H + h;
    if constexpr (RECUR) {
        const float gl = gleak[h], vl = vleak[h], c0 = cm[h];
        const float vp = vsrc[bh];               // K==H here
        float num = fmaf(c0, vp, gl * vl) + n + snum[bh];
        float den = c0 + gl + d + sden[bh];
        vout[bh] = num * __builtin_amdgcn_rcpf(den + 1e-8f);
    } else {
        onum[bh] = n;
        oden[bh] = d;
    }
}

extern "C" void kernel_launch(void* const* d_in, const int* in_sizes, int n_in,
                              void* d_out, int out_size, void* d_ws, size_t ws_size,
                              hipStream_t stream) {
    const float* inputs = (const float*)d_in[0];   // B x I
    const float* state  = (const float*)d_in[1];   // B x H
    const float* smu    = (const float*)d_in[2];   // I x H
    const float* ssig   = (const float*)d_in[3];
    const float* sW     = (const float*)d_in[4];
    const float* serev  = (const float*)d_in[5];
    const float* mu     = (const float*)d_in[6];   // H x H
    const float* sig    = (const float*)d_in[7];
    const float* W      = (const float*)d_in[8];
    const float* erev   = (const float*)d_in[9];
    const float* vleak  = (const float*)d_in[10];  // H
    const float* gleak  = (const float*)d_in[11];
    const float* cm     = (const float*)d_in[12];

    float* out  = (float*)d_out;                   // B x H
    char*  ws   = (char*)d_ws;
    float* snum = (float*)(ws);                              // 1MB
    float* sden = (float*)(ws + 1 * 1048576);                // 1MB
    float* vA   = (float*)(ws + 2 * 1048576);                // 1MB ping buffer
    H4x2*  rslab = (H4x2*)(ws + 3 * 1048576);                // 2MB (H x H)
    H4x2*  sslab = (H4x2*)(ws + 5 * 1048576);                // 1MB (I x H)

    // Prep: transform + relayout weights once per launch.
    ltc_prep<<<(LTC_H * LTC_H + 255) / 256, 256, 0, stream>>>(mu, sig, W, erev, rslab, LTC_H);
    ltc_prep<<<(LTC_I * LTC_H + 255) / 256, 256, 0, stream>>>(smu, ssig, sW, serev, sslab, LTC_I);

    dim3 grid(LTC_H / 64, LTC_B / 4);              // (8, 128) = 1024 blocks
    dim3 blk(256);

    // Sensory pass: raw sums into ws.
    ltc_pass<LTC_I, false><<<grid, blk, 0, stream>>>(
        inputs, sslab, nullptr, nullptr, nullptr, nullptr, nullptr,
        snum, sden, nullptr);

    // 6 unfolds, ping-ponging so the last lands in d_out.
    const float* vin = state;
    float* targets[6] = {vA, out, vA, out, vA, out};
    for (int s = 0; s < 6; ++s) {
        ltc_pass<LTC_H, true><<<grid, blk, 0, stream>>>(
            vin, rslab, snum, sden, vleak, gleak, cm,
            nullptr, nullptr, targets[s]);
        vin = targets[s];
    }
}

// Round 4
// 334.401 us; speedup vs baseline: 1.1656x; 1.0051x over previous
//
#include <hip/hip_runtime.h>

#define LTC_B 512
#define LTC_H 512
#define LTC_I 256

static constexpr float kL2E = 1.4426950408889634f;  // log2(e)

// Pre-transformed weight pair (2 j's for one h), 16B:
// t = a*v + c (log2 domain), sig = 1/(1+2^t), n += wz*sig, d += wd*sig.
struct alignas(16) HPair { _Float16 a0, a1, c0, c1, wz0, wz1, wd0, wd1; };

typedef unsigned int u32;
#define AS_G __attribute__((address_space(1)))
#define AS_L __attribute__((address_space(3)))

__device__ __forceinline__ void ldg_lds16(const void* g, void* l) {
    // async global->LDS DMA, 16B/lane; LDS dest = wave-uniform base + lane*16
    __builtin_amdgcn_global_load_lds((const AS_G u32*)g, (AS_L u32*)l, 16, 0, 0);
}

// slab unit ((ht*(K/2) + jp)*64 + hh) holds j=2jp,2jp+1 for h=ht*64+hh.
// A 32-j chunk of one h-tile = contiguous 16KB -> DMA staging, zero addr VALU.
template<int K>
__global__ void ltc_prep(const float* __restrict__ mu, const float* __restrict__ sigma,
                         const float* __restrict__ W, const float* __restrict__ erev,
                         HPair* __restrict__ slab) {
    const int t = blockIdx.x * 256 + threadIdx.x;   // one thread per 16B unit
    if (t >= K * 256) return;
    const int hh   = t & 63;
    const int rest = t >> 6;
    const int jp   = rest & (K / 2 - 1);
    const int ht   = rest / (K / 2);
    const int h    = ht * 64 + hh;
    const int g0   = (2 * jp) * LTC_H + h;
    const int g1   = g0 + LTC_H;
    HPair o;
    o.a0 = (_Float16)(-sigma[g0] * kL2E);
    o.a1 = (_Float16)(-sigma[g1] * kL2E);
    o.c0 = (_Float16)(mu[g0] * sigma[g0] * kL2E);
    o.c1 = (_Float16)(mu[g1] * sigma[g1] * kL2E);
    o.wz0 = (_Float16)(W[g0] * erev[g0]);
    o.wz1 = (_Float16)(W[g1] * erev[g1]);
    o.wd0 = (_Float16)(W[g0]);
    o.wd1 = (_Float16)(W[g1]);
    slab[t] = o;
}

// Block = 256 thr (4 waves), wave owns 1 b-row x 64 h. Grid (8, B/4) = 1024
// blocks -> 4 blocks/CU. Chunk order rotated per block so co-resident blocks
// hit their barrier drains at different phases (sum is order-independent).
template<int K, bool RECUR>
__global__ __launch_bounds__(256, 4)
void ltc_pass(const float* __restrict__ vsrc,    // B x K
              const HPair* __restrict__ slab,    // [8][K/2][64]
              const float* __restrict__ snum, const float* __restrict__ sden,
              const float* __restrict__ vleak, const float* __restrict__ gleak,
              const float* __restrict__ cm,
              float* __restrict__ onum, float* __restrict__ oden,
              float* __restrict__ vout)
{
    __shared__ HPair wbuf[2][16 * 64];           // 2 x 16KB
    const int tid  = threadIdx.x;
    const int lane = tid & 63;
    const int wu   = __builtin_amdgcn_readfirstlane(tid >> 6);  // uniform wave id
    const int ht   = blockIdx.x;                 // 0..7
    const int b    = blockIdx.y * 4 + wu;        // uniform per wave
    const float* __restrict__ vrow = vsrc + (size_t)b * K;  // uniform -> s_load

    constexpr int NC = K / 32;
    const int rot = (int)((blockIdx.x + 7u * blockIdx.y) & (NC - 1));
    const char* slabt = (const char*)slab + (size_t)ht * (K * 512);

    // prefetch first chunk
    {
        const char* src = slabt + rot * 16384 + wu * 4096;
        char* dst = (char*)&wbuf[0][0] + wu * 4096;
        #pragma unroll
        for (int rr = 0; rr < 4; ++rr)
            ldg_lds16(src + rr * 1024 + lane * 16, dst + rr * 1024);
    }

    float na = 0.f, da = 0.f;

    #pragma unroll
    for (int i = 0; i < NC; ++i) {
        const int c = (rot + i) & (NC - 1);
        __syncthreads();                         // drains chunk i's DMA + joins
        if (i + 1 < NC) {                        // DMA i+1 flies during compute i
            const int cn = (rot + i + 1) & (NC - 1);
            const char* src = slabt + cn * 16384 + wu * 4096;
            char* dst = (char*)&wbuf[(i + 1) & 1][0] + wu * 4096;
            #pragma unroll
            for (int rr = 0; rr < 4; ++rr)
                ldg_lds16(src + rr * 1024 + lane * 16, dst + rr * 1024);
        }
        const HPair* wb = &wbuf[i & 1][0];
        const float* __restrict__ vch = vrow + c * 32;

        HPair pr[16];                            // 64 VGPRs: grouped ds_read_b128
        #pragma unroll
        for (int jj = 0; jj < 16; ++jj) pr[jj] = wb[jj * 64 + lane];

        #pragma unroll
        for (int jj = 0; jj < 16; ++jj) {
            const float vj0 = vch[2 * jj];       // uniform scalar loads
            const float vj1 = vch[2 * jj + 1];
            const float t0 = fmaf((float)pr[jj].a0, vj0, (float)pr[jj].c0);
            const float t1 = fmaf((float)pr[jj].a1, vj1, (float)pr[jj].c1);
            const float e0 = __builtin_amdgcn_exp2f(t0);
            const float e1 = __builtin_amdgcn_exp2f(t1);
            const float d0 = 1.0f + e0;
            const float d1 = 1.0f + e1;
            const float rr = __builtin_amdgcn_rcpf(d0 * d1);  // 1 rcp for 2 sigmoids
            const float s0 = rr * d1;
            const float s1 = rr * d0;
            na = fmaf((float)pr[jj].wz0, s0, na);
            da = fmaf((float)pr[jj].wd0, s0, da);
            na = fmaf((float)pr[jj].wz1, s1, na);
            da = fmaf((float)pr[jj].wd1, s1, da);
        }
    }

    const int h  = ht * 64 + lane;
    const int bh = b * LTC_H + h;
    if constexpr (RECUR) {
        const float gl = gleak[h], vl = vleak[h], c0 = cm[h];
        const float vp = vsrc[bh];               // K==H here
        const float num = fmaf(c0, vp, gl * vl) + na + snum[bh];
        const float den = c0 + gl + da + sden[bh];
        vout[bh] = num * __builtin_amdgcn_rcpf(den + 1e-8f);
    } else {
        onum[bh] = na;
        oden[bh] = da;
    }
}

extern "C" void kernel_launch(void* const* d_in, const int* in_sizes, int n_in,
                              void* d_out, int out_size, void* d_ws, size_t ws_size,
                              hipStream_t stream) {
    const float* inputs = (const float*)d_in[0];   // B x I
    const float* state  = (const float*)d_in[1];   // B x H
    const float* smu    = (const float*)d_in[2];   // I x H
    const float* ssig   = (const float*)d_in[3];
    const float* sW     = (const float*)d_in[4];
    const float* serev  = (const float*)d_in[5];
    const float* mu     = (const float*)d_in[6];   // H x H
    const float* sig    = (const float*)d_in[7];
    const float* W      = (const float*)d_in[8];
    const float* erev   = (const float*)d_in[9];
    const float* vleak  = (const float*)d_in[10];  // H
    const float* gleak  = (const float*)d_in[11];
    const float* cm     = (const float*)d_in[12];

    float* out  = (float*)d_out;                   // B x H
    char*  ws   = (char*)d_ws;
    float* snum = (float*)(ws);                              // 1MB
    float* sden = (float*)(ws + 1 * 1048576);                // 1MB
    float* vA   = (float*)(ws + 2 * 1048576);                // 1MB ping buffer
    HPair* rslab = (HPair*)(ws + 3 * 1048576);               // 2MB (H x H)
    HPair* sslab = (HPair*)(ws + 5 * 1048576);               // 1MB (I x H)

    // Prep: transform + pair-pack weights once per launch (coalesced 16B writes).
    ltc_prep<LTC_H><<<LTC_H * 256 / 256, 256, 0, stream>>>(mu, sig, W, erev, rslab);
    ltc_prep<LTC_I><<<LTC_I * 256 / 256, 256, 0, stream>>>(smu, ssig, sW, serev, sslab);

    dim3 grid(LTC_H / 64, LTC_B / 4);              // (8, 128) = 1024 blocks
    dim3 blk(256);

    // Sensory pass: raw sums into ws.
    ltc_pass<LTC_I, false><<<grid, blk, 0, stream>>>(
        inputs, sslab, nullptr, nullptr, nullptr, nullptr, nullptr,
        snum, sden, nullptr);

    // 6 unfolds, ping-ponging so the last lands in d_out.
    const float* vin = state;
    float* targets[6] = {vA, out, vA, out, vA, out};
    for (int s = 0; s < 6; ++s) {
        ltc_pass<LTC_H, true><<<grid, blk, 0, stream>>>(
            vin, rslab, snum, sden, vleak, gleak, cm,
            nullptr, nullptr, targets[s]);
        vin = targets[s];
    }
}